// Round 1
// baseline (275.189 us; speedup 1.0000x reference)
//
#include <hip/hip_runtime.h>
#include <math.h>

#define B_TOTAL   16384
#define N_DENSE   13
#define N_TABLES  26
#define V_ROWS    1000000
#define E_DIM     2
#define SPLIT     4   // lanes cooperating per sample

__global__ __launch_bounds__(64) void dlrm_fused_kernel(
    const float* __restrict__ x_dense,   // [B,13]
    const int*   __restrict__ x_cat,     // [B,26]
    const float* __restrict__ emb,       // [26,1000000,2]
    const float* __restrict__ bw1,       // [13,3]
    const float* __restrict__ bb1,       // [3]
    const float* __restrict__ bw2,       // [3,2]
    const float* __restrict__ bb2,       // [2]
    const float* __restrict__ tw1,       // [54,4]
    const float* __restrict__ tb1,       // [4]
    const float* __restrict__ tw2,       // [4,2]
    const float* __restrict__ tb2,       // [2]
    const float* __restrict__ tw3,       // [2,1]
    const float* __restrict__ tb3,       // [1]
    float*       __restrict__ out)       // [B,1]
{
    const int gtid = blockIdx.x * blockDim.x + threadIdx.x;
    const int b = gtid >> 2;          // sample index
    const int r = gtid & 3;           // lane-within-quad
    if (b >= B_TOTAL) return;

    // ---- this lane's 6-7 embedding gathers, issued as early as possible ----
    // lane r owns tables t = r, r+4, ..., (7 tables for r<2, 6 for r>=2)
    const int cbase = b * N_TABLES;
    float2 ev[6];
    #pragma unroll
    for (int k = 0; k < 6; ++k) {
        const int t   = r + 4 * k;
        const int idx = x_cat[cbase + t];
        ev[k] = *reinterpret_cast<const float2*>(
            emb + ((size_t)t * V_ROWS + (size_t)idx) * E_DIM);
    }
    const int t6 = 24 + r;            // valid table only for r<2
    float2 ev6 = make_float2(0.0f, 0.0f);
    if (r < 2) {
        const int idx = x_cat[cbase + t6];
        ev6 = *reinterpret_cast<const float2*>(
            emb + ((size_t)t6 * V_ROWS + (size_t)idx) * E_DIM);
    }

    // ---- bottom MLP 13->3->2 (computed redundantly by all 4 quad lanes;
    //      same addresses -> broadcast loads, avoids divergence/shuffles) ----
    float xd[N_DENSE];
    const int dbase = b * N_DENSE;
    #pragma unroll
    for (int i = 0; i < N_DENSE; ++i) xd[i] = x_dense[dbase + i];
    float d1[3];
    #pragma unroll
    for (int j = 0; j < 3; ++j) {
        float acc = bb1[j];
        #pragma unroll
        for (int i = 0; i < N_DENSE; ++i) acc = fmaf(xd[i], bw1[i * 3 + j], acc);
        d1[j] = fmaxf(acc, 0.0f);
    }
    float d2[2];
    #pragma unroll
    for (int j = 0; j < 2; ++j) {
        float acc = bb2[j];
        #pragma unroll
        for (int i = 0; i < 3; ++i) acc = fmaf(d1[i], bw2[i * 2 + j], acc);
        d2[j] = fmaxf(acc, 0.0f);
    }

    // ---- partial h1 over this lane's tables ----
    // reference layout: ev element 2t   -> tw1 row (2+2t)
    //                   ev element 2t+1 -> tw1 row (3+2t)
    float h1p[4] = {0.0f, 0.0f, 0.0f, 0.0f};
    #pragma unroll
    for (int k = 0; k < 6; ++k) {
        const int t = r + 4 * k;
        #pragma unroll
        for (int j = 0; j < 4; ++j) {
            h1p[j] = fmaf(ev[k].x, tw1[(2 + 2 * t) * 4 + j], h1p[j]);
            h1p[j] = fmaf(ev[k].y, tw1[(3 + 2 * t) * 4 + j], h1p[j]);
        }
    }
    if (r < 2) {   // keep the OOB tw1 rows (t>=26) untouched
        #pragma unroll
        for (int j = 0; j < 4; ++j) {
            h1p[j] = fmaf(ev6.x, tw1[(2 + 2 * t6) * 4 + j], h1p[j]);
            h1p[j] = fmaf(ev6.y, tw1[(3 + 2 * t6) * 4 + j], h1p[j]);
        }
    }

    // ---- quad reduction: xor-1 and xor-2 stay inside each 4-lane group ----
    #pragma unroll
    for (int j = 0; j < 4; ++j) {
        h1p[j] += __shfl_xor(h1p[j], 1);
        h1p[j] += __shfl_xor(h1p[j], 2);
    }

    // ---- finish top MLP (all 4 lanes redundantly; lane 0 stores) ----
    float h1[4];
    #pragma unroll
    for (int j = 0; j < 4; ++j) {
        float acc = tb1[j] + h1p[j];
        acc = fmaf(d2[0], tw1[0 * 4 + j], acc);
        acc = fmaf(d2[1], tw1[1 * 4 + j], acc);
        h1[j] = fmaxf(acc, 0.0f);
    }
    float h2[2];
    #pragma unroll
    for (int j = 0; j < 2; ++j) {
        float acc = tb2[j];
        #pragma unroll
        for (int i = 0; i < 4; ++i) acc = fmaf(h1[i], tw2[i * 2 + j], acc);
        h2[j] = fmaxf(acc, 0.0f);
    }
    float z = tb3[0];
    z = fmaf(h2[0], tw3[0], z);
    z = fmaf(h2[1], tw3[1], z);

    if (r == 0) out[b] = 1.0f / (1.0f + expf(-z));
}

extern "C" void kernel_launch(void* const* d_in, const int* in_sizes, int n_in,
                              void* d_out, int out_size, void* d_ws, size_t ws_size,
                              hipStream_t stream) {
    const float* x_dense = (const float*)d_in[0];
    const int*   x_cat   = (const int*)  d_in[1];
    const float* emb     = (const float*)d_in[2];
    const float* bw1     = (const float*)d_in[3];
    const float* bb1     = (const float*)d_in[4];
    const float* bw2     = (const float*)d_in[5];
    const float* bb2     = (const float*)d_in[6];
    const float* tw1     = (const float*)d_in[7];
    const float* tb1     = (const float*)d_in[8];
    const float* tw2     = (const float*)d_in[9];
    const float* tb2     = (const float*)d_in[10];
    const float* tw3     = (const float*)d_in[11];
    const float* tb3     = (const float*)d_in[12];
    float* out = (float*)d_out;

    // 4 lanes/sample: 65536 threads = 1024 waves -> all 4 SIMDs of every CU
    // active (vs 256 waves = 1 SIMD/CU before), 4 blocks/CU of balance slack.
    const int block = 64;
    const int grid  = (B_TOTAL * SPLIT + block - 1) / block;   // 1024
    dlrm_fused_kernel<<<grid, block, 0, stream>>>(
        x_dense, x_cat, emb, bw1, bb1, bw2, bb2,
        tw1, tb1, tw2, tb2, tw3, tb3, out);
}